// Round 8
// baseline (1173.025 us; speedup 1.0000x reference)
//
#include <hip/hip_runtime.h>
#include <hip/hip_bf16.h>

#define Bn 2
#define Sn 4096
#define Dn 512
#define Hn 8
#define DKn 64

typedef __attribute__((ext_vector_type(8))) short bf16x8;
typedef __attribute__((ext_vector_type(4))) float f32x4;
typedef __attribute__((ext_vector_type(4))) _Float16 f16x4;
typedef __attribute__((ext_vector_type(8))) _Float16 f16x8;
typedef __attribute__((ext_vector_type(2))) _Float16 f16x2;
typedef __attribute__((ext_vector_type(8))) unsigned short us8;
typedef __attribute__((ext_vector_type(4))) unsigned short us4;

__device__ __forceinline__ unsigned short f2bf(float f) {
  unsigned u = __builtin_bit_cast(unsigned, f);
  u += 0x7fffu + ((u >> 16) & 1u);   // RNE; inputs finite
  return (unsigned short)(u >> 16);
}

// gfx950 packed fp32->bf16 (RNE). lo -> D[15:0], hi -> D[31:16].
__device__ __forceinline__ unsigned cvtpk_bf16(float lo, float hi) {
  unsigned r;
  asm("v_cvt_pk_bf16_f32 %0, %1, %2" : "=v"(r) : "v"(lo), "v"(hi));
  return r;
}

// bit j of byte -> bit 4j (for interleaved mask repack; pm stays bit-identical)
__device__ __forceinline__ unsigned spread4(unsigned x) {
  x = (x | (x << 12)) & 0x000F000Fu;
  x = (x | (x << 6)) & 0x03030303u;
  x = (x | (x << 3)) & 0x11111111u;
  return x;
}

// -------------------------------------------------------------------- prep
// blockIdx.x < 256 : weights -> bf16 W^T tiles (Q-scale folded into w_q).
// blockIdx.x >= 256: mask 32:1 bit-pack, transposed pm[b][kvw][q]. int4
// vectorized (1KB/wave/instr): 4x ballot + spread4 interleave; pm output is
// bit-identical to the scalar path (R4 and earlier).
__global__ __launch_bounds__(256) void prep_k(
    const int* __restrict__ mask, unsigned int* __restrict__ pm,
    const float* __restrict__ wq, const float* __restrict__ wk,
    const float* __restrict__ wv, const float* __restrict__ wo,
    unsigned short* __restrict__ wt) {
  const int t = threadIdx.x;
  if (blockIdx.x < 256) {
    __shared__ unsigned short ls[64][68];
    int bid = blockIdx.x;
    int z = bid >> 6, x = bid & 7, y = (bid >> 3) & 7;
    const float* W = z == 0 ? wq : z == 1 ? wk : z == 2 ? wv : wo;
    // fold softmax scale (1/sqrt(dk) * log2e) into W_q so GEMM epilogue is a
    // plain cvt and flash_k's exp2 needs no extra multiply.
    const float wsc = (z == 0) ? 0.18033688011112042f : 1.0f;
    int k0 = x * 64, n0 = y * 64;
    for (int j = 0; j < 4; ++j) {
      int i = t + j * 256;
      int r = i >> 4, c4 = (i & 15) << 2;
      float4 f = *(const float4*)&W[(size_t)(k0 + r) * 512 + n0 + c4];
      ls[c4 + 0][r] = f2bf(f.x * wsc);
      ls[c4 + 1][r] = f2bf(f.y * wsc);
      ls[c4 + 2][r] = f2bf(f.z * wsc);
      ls[c4 + 3][r] = f2bf(f.w * wsc);
    }
    __syncthreads();
    unsigned short* out = wt + (size_t)z * 512 * 512;
    for (int j = 0; j < 4; ++j) {
      int i = t + j * 256;
      int r = i >> 4, c4 = (i & 15) << 2;
      us4 v = {ls[r][c4], ls[r][c4 + 1], ls[r][c4 + 2], ls[r][c4 + 3]};
      *(us4*)&out[(size_t)(n0 + r) * 512 + k0 + c4] = v;
    }
  } else {
    // 4096 mask blocks x 256 thr x 8 it x int4 = 2*4096*4096 elements
    size_t gt = (size_t)(blockIdx.x - 256) * 256 + t;   // int4 index
    for (int it = 0; it < 8; ++it, gt += 1048576) {
      size_t e0 = gt * 4;                                // element index
      int4 mv = *(const int4*)&mask[e0];
      unsigned long long bl0 = __ballot(mv.x != 0);
      unsigned long long bl1 = __ballot(mv.y != 0);
      unsigned long long bl2 = __ballot(mv.z != 0);
      unsigned long long bl3 = __ballot(mv.w != 0);
      if ((t & 63) < 8) {
        int wd = t & 7;
        unsigned word = spread4((unsigned)(bl0 >> (wd * 8)) & 0xFFu) |
                        (spread4((unsigned)(bl1 >> (wd * 8)) & 0xFFu) << 1) |
                        (spread4((unsigned)(bl2 >> (wd * 8)) & 0xFFu) << 2) |
                        (spread4((unsigned)(bl3 >> (wd * 8)) & 0xFFu) << 3);
        size_t eb = e0 & ~(size_t)255;     // wave-base element (256-aligned)
        int qq = (int)((eb >> 12) & 4095);
        int bb = (int)(eb >> 24);
        int kvw = (int)((eb >> 5) & 127) + wd;
        pm[((size_t)bb * 128 + kvw) * 4096 + qq] = word;
      }
    }
  }
}

// ------------------------------------------------------------------- GEMM
// C[8192,512] = A @ W[512,512]. BM=MT*64, BN=128, BK=64, 4 waves, LDS
// double-buffered, ONE barrier per k-tile. HEADS: A is fp32 (cvt fused in
// staging via v_cvt_pk_bf16_f32); z<2 -> bf16 heads, z==2 -> f16 V^T
// pos-permuted via in-LDS transpose. !HEADS: A bf16, fp32 linear out.
template <int MT, bool HEADS>
__global__ __launch_bounds__(256, 2) void gemm_k(
    const float* __restrict__ aq, const float* __restrict__ ak,
    const float* __restrict__ av, const unsigned short* __restrict__ abf,
    const unsigned short* __restrict__ wt, unsigned short* __restrict__ oh,
    unsigned short* __restrict__ vtg, float* __restrict__ olin) {
  __shared__ unsigned short smem[MT * 8192 + 16384];  // As[2] | Bs[2]
  const int z = blockIdx.z;
  const float* A32 = HEADS ? (z == 0 ? aq : z == 1 ? ak : av) : nullptr;
  const unsigned short* Wt = wt + (size_t)z * 512 * 512;
  const int m0 = blockIdx.x * (MT * 64), n0 = blockIdx.y * 128;
  const int t = threadIdx.x, w = t >> 6, l = t & 63;
  const int quad = l >> 4, c = l & 15;

  f32x4 acc[MT][8] = {};
  us8 apre[MT * 2], bpre[4];

  auto ldA = [&](int j, int kk) -> us8 {
    int i = t + j * 256, r = i >> 3, u = i & 7;
    if constexpr (HEADS) {
      const float* s = &A32[(size_t)(m0 + r) * 512 + kk + (u << 3)];
      float4 f0 = *(const float4*)s;
      float4 f1 = *(const float4*)(s + 4);
      uint4 p;
      p.x = cvtpk_bf16(f0.x, f0.y);
      p.y = cvtpk_bf16(f0.z, f0.w);
      p.z = cvtpk_bf16(f1.x, f1.y);
      p.w = cvtpk_bf16(f1.z, f1.w);
      return __builtin_bit_cast(us8, p);
    } else {
      return *(const us8*)&abf[(size_t)(m0 + r) * 512 + kk + (u << 3)];
    }
  };

#pragma unroll
  for (int j = 0; j < MT * 2; ++j) apre[j] = ldA(j, 0);
#pragma unroll
  for (int j = 0; j < 4; ++j) {
    int i = t + j * 256, r = i >> 3, u = i & 7;
    bpre[j] = *(const us8*)&Wt[(size_t)(n0 + r) * 512 + (u << 3)];
  }
#pragma unroll
  for (int j = 0; j < MT * 2; ++j) {   // stage buf 0
    int i = t + j * 256, r = i >> 3, u = i & 7;
    *(us8*)&smem[r * 64 + ((u ^ (r & 7)) << 3)] = apre[j];
  }
#pragma unroll
  for (int j = 0; j < 4; ++j) {
    int i = t + j * 256, r = i >> 3, u = i & 7;
    *(us8*)&smem[MT * 8192 + r * 64 + ((u ^ (r & 7)) << 3)] = bpre[j];
  }

  for (int k0 = 0; k0 < 512; k0 += 64) {
    const int cur = (k0 >> 6) & 1;
    const unsigned short* AsC = &smem[cur * (MT * 4096)];
    const unsigned short* BsC = &smem[MT * 8192 + cur * 8192];
    __syncthreads();
    const bool nxt = k0 + 64 < 512;
    if (nxt) {
#pragma unroll
      for (int j = 0; j < MT * 2; ++j) apre[j] = ldA(j, k0 + 64);
#pragma unroll
      for (int j = 0; j < 4; ++j) {
        int i = t + j * 256, r = i >> 3, u = i & 7;
        bpre[j] = *(const us8*)&Wt[(size_t)(n0 + r) * 512 + k0 + 64 + (u << 3)];
      }
    }

#pragma unroll
    for (int kc = 0; kc < 2; ++kc) {
      bf16x8 aA[MT], bB[8];
      int u = kc * 4 + quad;
#pragma unroll
      for (int mt = 0; mt < MT; ++mt) {
        int row = w * (MT * 16) + mt * 16 + c;
        aA[mt] = *(const bf16x8*)&AsC[row * 64 + ((u ^ (c & 7)) << 3)];
      }
#pragma unroll
      for (int nt = 0; nt < 8; ++nt) {
        int row = nt * 16 + c;
        bB[nt] = *(const bf16x8*)&BsC[row * 64 + ((u ^ (c & 7)) << 3)];
      }
      __builtin_amdgcn_s_setprio(1);
#pragma unroll
      for (int mt = 0; mt < MT; ++mt)
#pragma unroll
        for (int nt = 0; nt < 8; ++nt)
          acc[mt][nt] = __builtin_amdgcn_mfma_f32_16x16x32_bf16(
              aA[mt], bB[nt], acc[mt][nt], 0, 0, 0);
      __builtin_amdgcn_s_setprio(0);
    }

    if (nxt) {
      unsigned short* AsN = &smem[(cur ^ 1) * (MT * 4096)];
      unsigned short* BsN = &smem[MT * 8192 + (cur ^ 1) * 8192];
#pragma unroll
      for (int j = 0; j < MT * 2; ++j) {
        int i = t + j * 256, r = i >> 3, u = i & 7;
        *(us8*)&AsN[r * 64 + ((u ^ (r & 7)) << 3)] = apre[j];
      }
#pragma unroll
      for (int j = 0; j < 4; ++j) {
        int i = t + j * 256, r = i >> 3, u = i & 7;
        *(us8*)&BsN[r * 64 + ((u ^ (r & 7)) << 3)] = bpre[j];
      }
    }
  }

  if constexpr (HEADS) {
    if (z == 2) {
      // ---- V^T epilogue via LDS transpose (pitch 152 shorts) ----
      __syncthreads();
#pragma unroll
      for (int mt = 0; mt < MT; ++mt) {
        int mb = w * (MT * 16) + mt * 16 + (quad << 2);
        int ml = (mb & 64) | (((mb >> 5) & 1) << 5) | (((mb >> 2) & 3) << 3) |
                 (((mb >> 4) & 1) << 2);                  // pos-permuted coord
#pragma unroll
        for (int nt = 0; nt < 8; ++nt) {
          int nl = nt * 16 + c;
          us4 pk;
#pragma unroll
          for (int r = 0; r < 4; ++r)
            pk[r] = __builtin_bit_cast(unsigned short, (_Float16)acc[mt][nt][r]);
          *(us4*)&smem[nl * 152 + ml] = pk;
        }
      }
      __syncthreads();
      const int bb = m0 >> 12, sb = m0 & 4095;
#pragma unroll
      for (int j = 0; j < MT * 4; ++j) {
        int i = t + j * 256;
        int nl = i >> 4, mc = (i & 15) << 3;
        us8 vv = *(const us8*)&smem[nl * 152 + mc];
        int n = n0 + nl, hh = n >> 6, dk = n & 63;
        *(us8*)&vtg[((size_t)(bb * Hn + hh) * DKn + dk) * Sn + sb + mc] = vv;
      }
    } else {
#pragma unroll
      for (int mt = 0; mt < MT; ++mt)
#pragma unroll
        for (int nt = 0; nt < 8; ++nt) {
          int m = m0 + w * (MT * 16) + mt * 16 + (quad << 2);
          int n = n0 + nt * 16 + c;
          int b = m >> 12, s = m & 4095, hh = n >> 6, dk = n & 63;
          unsigned short* dst = &oh[(size_t)z * (Bn * Hn * Sn * DKn) +
                                    ((size_t)(b * Hn + hh) * Sn + s) * DKn + dk];
          unsigned pk0 = cvtpk_bf16(acc[mt][nt][0], acc[mt][nt][1]);
          unsigned pk1 = cvtpk_bf16(acc[mt][nt][2], acc[mt][nt][3]);
          dst[0] = (unsigned short)pk0;
          dst[DKn] = (unsigned short)(pk0 >> 16);
          dst[2 * DKn] = (unsigned short)pk1;
          dst[3 * DKn] = (unsigned short)(pk1 >> 16);
        }
    }
  } else {
#pragma unroll
    for (int mt = 0; mt < MT; ++mt)
#pragma unroll
      for (int nt = 0; nt < 8; ++nt)
#pragma unroll
        for (int r = 0; r < 4; ++r) {
          int m = m0 + w * (MT * 16) + mt * 16 + (quad << 2) + r;
          int n = n0 + nt * 16 + c;
          olin[(size_t)m * 512 + n] = acc[mt][nt][r];
        }
  }
}

// ------------------------------------------------------------- flash attn
// 1024 thr = 4 kv-groups x 4 waves x 32 q (full-occupancy variant: 512
// blocks x 1024 thr = 524288 threads = 2048/CU = 32 waves/CU at 2 blk/CU).
// Each group stages 32 KV/iter (K 4KB + V^T 4KB + 1 pm word/q); 32 iters.
// Static-max softmax; P in regs; rowsum via ones-MFMA; PV f16 K=32.
// Mask = AND on packed f16 P via conflict-free 16-entry LDS table.
// h = bid&7 pins each head's K/V to one XCD L2 (T1, R4-measured FETCH win).
// R2/R3 lessons kept: prefetch issued immediately post-barrier; NO s_setprio
// here (fences -> spill storm, WRITE 16->525MB).
__global__ __launch_bounds__(1024, 8) void flash_k(
    const unsigned short* __restrict__ Qh, const unsigned short* __restrict__ Kh,
    const unsigned short* __restrict__ VtG, const unsigned int* __restrict__ pmt,
    unsigned short* __restrict__ attn) {
  // SM layout (shorts): Ks[g][p] 8x2048 | Vts[g][p] 8x2048 @16384 | Mw @32768
  __shared__ unsigned short SM[34816];
  __shared__ unsigned long long MskT[16];        // nibble -> f16x4 AND mask

  const int bid = blockIdx.x;
  const int h = bid & 7;                 // XCD = id%8 -> head h pins to XCD h
  const int b = (bid >> 3) & 1;
  const int q0 = (bid >> 4) * 128;
  const int t = threadIdx.x;
  const int g = t >> 8, tg = t & 255;
  const int w = (t >> 6) & 3, l = t & 63;
  const int quad = l >> 4, c = l & 15;
  const size_t hb = (size_t)(b * Hn + h) * Sn * DKn;
  const unsigned short* Qg = Qh + hb;
  unsigned int* MwU = (unsigned int*)(SM + 32768);

  if (t < 16) {
    unsigned lo = ((t & 1) ? 0xFFFFu : 0u) | ((t & 2) ? 0xFFFF0000u : 0u);
    unsigned hi = ((t & 4) ? 0xFFFFu : 0u) | ((t & 8) ? 0xFFFF0000u : 0u);
    MskT[t] = ((unsigned long long)hi << 32) | lo;
  }

  bf16x8 bQ[2][2];
#pragma unroll
  for (int qf = 0; qf < 2; ++qf) {
    int qrow = q0 + w * 32 + qf * 16 + c;
#pragma unroll
    for (int kc = 0; kc < 2; ++kc)
      bQ[qf][kc] = *(const bf16x8*)&Qg[(size_t)qrow * 64 + kc * 32 + quad * 8];
  }

  f32x4 oacc[2][4] = {};
  f32x4 oaccl[2] = {};                 // rowsum frag: reg r <-> q = quad*4+r
  f16x8 vone8;
#pragma unroll
  for (int i = 0; i < 8; ++i) vone8[i] = (_Float16)1.0f;

  // staging thread maps: K row sr cols su*8 ; V dk row, pos pu*8
  const int sr = tg >> 3, su = tg & 7;
  const int dk = tg >> 2, pu = tg & 3;
  const int offK = sr * 64 + ((su ^ (sr & 7)) << 3);
  const int offV = dk * 32 + ((pu ^ ((dk >> 1) & 3)) << 3);

  const unsigned short* kp = Kh + hb + (size_t)(g * 32 + sr) * 64 + (su << 3);
  const unsigned short* vp = VtG + hb + (size_t)dk * Sn + g * 32 + (pu << 3);
  const unsigned int* mp =
      pmt + ((size_t)b * 128 + g) * 4096 + q0 + (tg & 127);

  us8 kpre, vpre;
  unsigned mpre;
  kpre = *(const us8*)kp;
  vpre = *(const us8*)vp;
  mpre = (tg < 128) ? *mp : 0u;
  *(us8*)&SM[(g << 1) * 2048 + offK] = kpre;
  *(us8*)&SM[16384 + (g << 1) * 2048 + offV] = vpre;
  if (tg < 128) MwU[(g << 1) * 128 + tg] = mpre;

  for (int it = 0; it < 32; ++it) {
    const int cur = it & 1;
    __syncthreads();
    const bool nxt = it + 1 < 32;
    // ---- issue next-tile global prefetch FIRST (R1/R2 lesson)
    if (nxt) {
      kp += 8192; vp += 128; mp += 16384;
      kpre = *(const us8*)kp;
      vpre = *(const us8*)vp;
      if (tg < 128) mpre = *mp;
    }

    const unsigned short* Ksb = &SM[((g << 1) | cur) * 2048];
    const unsigned short* Vtb = &SM[16384 + ((g << 1) | cur) * 2048];

    // ---- S^T = K . Q^T  (8 MFMAs)
    f32x4 sacc[2][2] = {};
#pragma unroll
    for (int kc = 0; kc < 2; ++kc) {
      int u = kc * 4 + quad;
#pragma unroll
      for (int kvt = 0; kvt < 2; ++kvt) {
        int row = kvt * 16 + c;
        bf16x8 aK = *(const bf16x8*)&Ksb[row * 64 + ((u ^ (c & 7)) << 3)];
#pragma unroll
        for (int qf = 0; qf < 2; ++qf)
          sacc[qf][kvt] = __builtin_amdgcn_mfma_f32_16x16x32_bf16(
              aK, bQ[qf][kc], sacc[qf][kvt], 0, 0, 0);
      }
    }

    // ---- unconditional exp2 -> packed f16, mask via LDS AND-table
    f16x8 ph[2];
#pragma unroll
    for (int qf = 0; qf < 2; ++qf) {
      int qloc = w * 32 + qf * 16 + c;
      unsigned wd = MwU[((g << 1) | cur) * 128 + qloc] >> (quad << 2);
      uint4 ww;
#pragma unroll
      for (int kvh = 0; kvh < 2; ++kvh) {
        const f32x4 s4 = sacc[qf][kvh];
        unsigned long long mk = MskT[(wd >> (kvh << 4)) & 15u];
        unsigned a = __builtin_bit_cast(
            unsigned, __builtin_amdgcn_cvt_pkrtz(
                          __builtin_amdgcn_exp2f(s4[0]),
                          __builtin_amdgcn_exp2f(s4[1])));
        unsigned bpk = __builtin_bit_cast(
            unsigned, __builtin_amdgcn_cvt_pkrtz(
                          __builtin_amdgcn_exp2f(s4[2]),
                          __builtin_amdgcn_exp2f(s4[3])));
        (&ww.x)[kvh * 2] = a & (unsigned)mk;
        (&ww.x)[kvh * 2 + 1] = bpk & (unsigned)(mk >> 32);
      }
      ph[qf] = __builtin_bit_cast(f16x8, ww);
    }

    // ---- O += P.V ; l += P.1  (10 MFMAs)
#pragma unroll
    for (int dkt = 0; dkt < 4; ++dkt) {
      int dk2 = dkt * 16 + c;
      f16x8 bV = __builtin_bit_cast(
          f16x8,
          *(const us8*)&Vtb[dk2 * 32 + ((quad ^ ((c >> 1) & 3)) << 3)]);
#pragma unroll
      for (int qf = 0; qf < 2; ++qf)
        oacc[qf][dkt] = __builtin_amdgcn_mfma_f32_16x16x32_f16(
            ph[qf], bV, oacc[qf][dkt], 0, 0, 0);
    }
#pragma unroll
    for (int qf = 0; qf < 2; ++qf)
      oaccl[qf] = __builtin_amdgcn_mfma_f32_16x16x32_f16(
          ph[qf], vone8, oaccl[qf], 0, 0, 0);

    if (nxt) {
      const int nb = cur ^ 1;
      *(us8*)&SM[((g << 1) | nb) * 2048 + offK] = kpre;
      *(us8*)&SM[16384 + ((g << 1) | nb) * 2048 + offV] = vpre;
      if (tg < 128) MwU[((g << 1) | nb) * 128 + tg] = mpre;
    }
  }

  // ---- combine 4 groups (3-slot tree, per-qf passes in reused LDS)
  __syncthreads();
  float* fs = (float*)SM;              // 3 slots x [dkt][w][l] f32x4 = 48 KB
  float* fl = (float*)(SM + 24576);    // 3 slots x [w][l] f32x4 = 12 KB
#pragma unroll
  for (int qf = 0; qf < 2; ++qf) {
    if (g > 0) {
      int slot = g - 1;
#pragma unroll
      for (int dkt = 0; dkt < 4; ++dkt)
        *(f32x4*)&fs[(((slot * 4 + dkt) * 4 + w) * 64 + l) * 4] = oacc[qf][dkt];
      *(f32x4*)&fl[(((slot * 4 + w)) * 64 + l) * 4] = oaccl[qf];
    }
    __syncthreads();
    if (g == 0) {
#pragma unroll
      for (int slot = 0; slot < 3; ++slot) {
        f32x4 l1 = *(const f32x4*)&fl[(((slot * 4 + w)) * 64 + l) * 4];
#pragma unroll
        for (int r = 0; r < 4; ++r) oaccl[qf][r] += l1[r];
#pragma unroll
        for (int dkt = 0; dkt < 4; ++dkt) {
          f32x4 o1 =
              *(const f32x4*)&fs[(((slot * 4 + dkt) * 4 + w) * 64 + l) * 4];
#pragma unroll
          for (int r = 0; r < 4; ++r) oacc[qf][dkt][r] += o1[r];
        }
      }
    }
    __syncthreads();
  }
  if (g == 0) {
#pragma unroll
    for (int qf = 0; qf < 2; ++qf)
#pragma unroll
      for (int r = 0; r < 4; ++r) {
        float invr = 1.0f / oaccl[qf][r];
        unsigned short* dst =
            &attn[((size_t)(b * Sn + q0 + w * 32 + qf * 16 + (quad << 2) + r)) * Dn +
                  h * 64 + c];
#pragma unroll
        for (int dkt = 0; dkt < 4; ++dkt)
          dst[dkt * 16] = f2bf(oacc[qf][dkt][r] * invr);
      }
  }
}

// ------------------------------------------------------------------ launch
extern "C" void kernel_launch(void* const* d_in, const int* in_sizes, int n_in,
                              void* d_out, int out_size, void* d_ws,
                              size_t ws_size, hipStream_t stream) {
  const float* q = (const float*)d_in[0];
  const float* k = (const float*)d_in[1];
  const float* v = (const float*)d_in[2];
  const int* mask = (const int*)d_in[3];
  const float* wq = (const float*)d_in[4];
  const float* wk = (const float*)d_in[5];
  const float* wv = (const float*)d_in[6];
  const float* wo = (const float*)d_in[7];
  float* out = (float*)d_out;

  char* ws = (char*)d_ws;
  const size_t headN = (size_t)Bn * Hn * Sn * DKn;        // 4,194,304 elems
  const size_t tensB = headN * 2;                          // 8 MB
  unsigned short* attn = (unsigned short*)ws;
  size_t off = 3 * tensB;
  unsigned short* qkv = (unsigned short*)(ws + off);       // Q,K heads + V^T
  off += 3 * tensB;
  unsigned short* wt = (unsigned short*)(ws + off);        // 2 MB
  off += 4ull * 512 * 512 * 2;
  unsigned int* pm = (unsigned int*)(ws + off);            // 4 MB transposed

  prep_k<<<4352, 256, 0, stream>>>(mask, pm, wq, wk, wv, wo, wt);
  gemm_k<2, true><<<dim3(64, 4, 3), 256, 0, stream>>>(
      q, k, v, nullptr, wt, qkv, qkv + 2 * headN, nullptr);
  flash_k<<<dim3(512), 1024, 0, stream>>>(qkv, qkv + headN,
                                          qkv + 2 * headN, pm, attn);
  gemm_k<1, false><<<dim3(128, 4, 1), 256, 0, stream>>>(
      nullptr, nullptr, nullptr, attn, wt + 3ull * 512 * 512, nullptr, nullptr,
      out);
}

// Round 9
// 348.898 us; speedup vs baseline: 3.3621x; 3.3621x over previous
//
#include <hip/hip_runtime.h>
#include <hip/hip_bf16.h>

#define Bn 2
#define Sn 4096
#define Dn 512
#define Hn 8
#define DKn 64

typedef __attribute__((ext_vector_type(8))) short bf16x8;
typedef __attribute__((ext_vector_type(4))) float f32x4;
typedef __attribute__((ext_vector_type(4))) _Float16 f16x4;
typedef __attribute__((ext_vector_type(8))) _Float16 f16x8;
typedef __attribute__((ext_vector_type(2))) _Float16 f16x2;
typedef __attribute__((ext_vector_type(8))) unsigned short us8;
typedef __attribute__((ext_vector_type(4))) unsigned short us4;

__device__ __forceinline__ unsigned short f2bf(float f) {
  unsigned u = __builtin_bit_cast(unsigned, f);
  u += 0x7fffu + ((u >> 16) & 1u);   // RNE; inputs finite
  return (unsigned short)(u >> 16);
}

// gfx950 packed fp32->bf16 (RNE). lo -> D[15:0], hi -> D[31:16].
__device__ __forceinline__ unsigned cvtpk_bf16(float lo, float hi) {
  unsigned r;
  asm("v_cvt_pk_bf16_f32 %0, %1, %2" : "=v"(r) : "v"(lo), "v"(hi));
  return r;
}

// bit j of byte -> bit 4j (for interleaved mask repack; pm stays bit-identical)
__device__ __forceinline__ unsigned spread4(unsigned x) {
  x = (x | (x << 12)) & 0x000F000Fu;
  x = (x | (x << 6)) & 0x03030303u;
  x = (x | (x << 3)) & 0x11111111u;
  return x;
}

// -------------------------------------------------------------------- prep
// blockIdx.x < 256 : weights -> bf16 W^T tiles (Q-scale folded into w_q).
// blockIdx.x >= 256: mask 32:1 bit-pack, transposed pm[b][kvw][q]. int4
// vectorized (1KB/wave/instr): 4x ballot + spread4 interleave.
__global__ __launch_bounds__(256) void prep_k(
    const int* __restrict__ mask, unsigned int* __restrict__ pm,
    const float* __restrict__ wq, const float* __restrict__ wk,
    const float* __restrict__ wv, const float* __restrict__ wo,
    unsigned short* __restrict__ wt) {
  const int t = threadIdx.x;
  if (blockIdx.x < 256) {
    __shared__ unsigned short ls[64][68];
    int bid = blockIdx.x;
    int z = bid >> 6, x = bid & 7, y = (bid >> 3) & 7;
    const float* W = z == 0 ? wq : z == 1 ? wk : z == 2 ? wv : wo;
    const float wsc = (z == 0) ? 0.18033688011112042f : 1.0f;
    int k0 = x * 64, n0 = y * 64;
    for (int j = 0; j < 4; ++j) {
      int i = t + j * 256;
      int r = i >> 4, c4 = (i & 15) << 2;
      float4 f = *(const float4*)&W[(size_t)(k0 + r) * 512 + n0 + c4];
      ls[c4 + 0][r] = f2bf(f.x * wsc);
      ls[c4 + 1][r] = f2bf(f.y * wsc);
      ls[c4 + 2][r] = f2bf(f.z * wsc);
      ls[c4 + 3][r] = f2bf(f.w * wsc);
    }
    __syncthreads();
    unsigned short* out = wt + (size_t)z * 512 * 512;
    for (int j = 0; j < 4; ++j) {
      int i = t + j * 256;
      int r = i >> 4, c4 = (i & 15) << 2;
      us4 v = {ls[r][c4], ls[r][c4 + 1], ls[r][c4 + 2], ls[r][c4 + 3]};
      *(us4*)&out[(size_t)(n0 + r) * 512 + k0 + c4] = v;
    }
  } else {
    size_t gt = (size_t)(blockIdx.x - 256) * 256 + t;   // int4 index
    for (int it = 0; it < 8; ++it, gt += 1048576) {
      size_t e0 = gt * 4;                                // element index
      int4 mv = *(const int4*)&mask[e0];
      unsigned long long bl0 = __ballot(mv.x != 0);
      unsigned long long bl1 = __ballot(mv.y != 0);
      unsigned long long bl2 = __ballot(mv.z != 0);
      unsigned long long bl3 = __ballot(mv.w != 0);
      if ((t & 63) < 8) {
        int wd = t & 7;
        unsigned word = spread4((unsigned)(bl0 >> (wd * 8)) & 0xFFu) |
                        (spread4((unsigned)(bl1 >> (wd * 8)) & 0xFFu) << 1) |
                        (spread4((unsigned)(bl2 >> (wd * 8)) & 0xFFu) << 2) |
                        (spread4((unsigned)(bl3 >> (wd * 8)) & 0xFFu) << 3);
        size_t eb = e0 & ~(size_t)255;     // wave-base element (256-aligned)
        int qq = (int)((eb >> 12) & 4095);
        int bb = (int)(eb >> 24);
        int kvw = (int)((eb >> 5) & 127) + wd;
        pm[((size_t)bb * 128 + kvw) * 4096 + qq] = word;
      }
    }
  }
}

// ------------------------------------------------------------------- GEMM
// C[8192,512] = A @ W[512,512]. BM=MT*64, BN=128, BK=64, 4 waves, LDS
// double-buffered, ONE barrier per k-tile. HEADS: A is fp32 (cvt fused in
// staging via v_cvt_pk_bf16_f32); z<2 -> bf16 heads, z==2 -> f16 V^T
// pos-permuted via in-LDS transpose. !HEADS: A bf16, fp32 linear out.
template <int MT, bool HEADS>
__global__ __launch_bounds__(256, 2) void gemm_k(
    const float* __restrict__ aq, const float* __restrict__ ak,
    const float* __restrict__ av, const unsigned short* __restrict__ abf,
    const unsigned short* __restrict__ wt, unsigned short* __restrict__ oh,
    unsigned short* __restrict__ vtg, float* __restrict__ olin) {
  __shared__ unsigned short smem[MT * 8192 + 16384];  // As[2] | Bs[2]
  const int z = blockIdx.z;
  const float* A32 = HEADS ? (z == 0 ? aq : z == 1 ? ak : av) : nullptr;
  const unsigned short* Wt = wt + (size_t)z * 512 * 512;
  const int m0 = blockIdx.x * (MT * 64), n0 = blockIdx.y * 128;
  const int t = threadIdx.x, w = t >> 6, l = t & 63;
  const int quad = l >> 4, c = l & 15;

  f32x4 acc[MT][8] = {};
  us8 apre[MT * 2], bpre[4];

  auto ldA = [&](int j, int kk) -> us8 {
    int i = t + j * 256, r = i >> 3, u = i & 7;
    if constexpr (HEADS) {
      const float* s = &A32[(size_t)(m0 + r) * 512 + kk + (u << 3)];
      float4 f0 = *(const float4*)s;
      float4 f1 = *(const float4*)(s + 4);
      uint4 p;
      p.x = cvtpk_bf16(f0.x, f0.y);
      p.y = cvtpk_bf16(f0.z, f0.w);
      p.z = cvtpk_bf16(f1.x, f1.y);
      p.w = cvtpk_bf16(f1.z, f1.w);
      return __builtin_bit_cast(us8, p);
    } else {
      return *(const us8*)&abf[(size_t)(m0 + r) * 512 + kk + (u << 3)];
    }
  };

#pragma unroll
  for (int j = 0; j < MT * 2; ++j) apre[j] = ldA(j, 0);
#pragma unroll
  for (int j = 0; j < 4; ++j) {
    int i = t + j * 256, r = i >> 3, u = i & 7;
    bpre[j] = *(const us8*)&Wt[(size_t)(n0 + r) * 512 + (u << 3)];
  }
#pragma unroll
  for (int j = 0; j < MT * 2; ++j) {   // stage buf 0
    int i = t + j * 256, r = i >> 3, u = i & 7;
    *(us8*)&smem[r * 64 + ((u ^ (r & 7)) << 3)] = apre[j];
  }
#pragma unroll
  for (int j = 0; j < 4; ++j) {
    int i = t + j * 256, r = i >> 3, u = i & 7;
    *(us8*)&smem[MT * 8192 + r * 64 + ((u ^ (r & 7)) << 3)] = bpre[j];
  }

  for (int k0 = 0; k0 < 512; k0 += 64) {
    const int cur = (k0 >> 6) & 1;
    const unsigned short* AsC = &smem[cur * (MT * 4096)];
    const unsigned short* BsC = &smem[MT * 8192 + cur * 8192];
    __syncthreads();
    const bool nxt = k0 + 64 < 512;
    if (nxt) {
#pragma unroll
      for (int j = 0; j < MT * 2; ++j) apre[j] = ldA(j, k0 + 64);
#pragma unroll
      for (int j = 0; j < 4; ++j) {
        int i = t + j * 256, r = i >> 3, u = i & 7;
        bpre[j] = *(const us8*)&Wt[(size_t)(n0 + r) * 512 + k0 + 64 + (u << 3)];
      }
    }

#pragma unroll
    for (int kc = 0; kc < 2; ++kc) {
      bf16x8 aA[MT], bB[8];
      int u = kc * 4 + quad;
#pragma unroll
      for (int mt = 0; mt < MT; ++mt) {
        int row = w * (MT * 16) + mt * 16 + c;
        aA[mt] = *(const bf16x8*)&AsC[row * 64 + ((u ^ (c & 7)) << 3)];
      }
#pragma unroll
      for (int nt = 0; nt < 8; ++nt) {
        int row = nt * 16 + c;
        bB[nt] = *(const bf16x8*)&BsC[row * 64 + ((u ^ (c & 7)) << 3)];
      }
      __builtin_amdgcn_s_setprio(1);
#pragma unroll
      for (int mt = 0; mt < MT; ++mt)
#pragma unroll
        for (int nt = 0; nt < 8; ++nt)
          acc[mt][nt] = __builtin_amdgcn_mfma_f32_16x16x32_bf16(
              aA[mt], bB[nt], acc[mt][nt], 0, 0, 0);
      __builtin_amdgcn_s_setprio(0);
    }

    if (nxt) {
      unsigned short* AsN = &smem[(cur ^ 1) * (MT * 4096)];
      unsigned short* BsN = &smem[MT * 8192 + (cur ^ 1) * 8192];
#pragma unroll
      for (int j = 0; j < MT * 2; ++j) {
        int i = t + j * 256, r = i >> 3, u = i & 7;
        *(us8*)&AsN[r * 64 + ((u ^ (r & 7)) << 3)] = apre[j];
      }
#pragma unroll
      for (int j = 0; j < 4; ++j) {
        int i = t + j * 256, r = i >> 3, u = i & 7;
        *(us8*)&BsN[r * 64 + ((u ^ (r & 7)) << 3)] = bpre[j];
      }
    }
  }

  if constexpr (HEADS) {
    if (z == 2) {
      // ---- V^T epilogue via LDS transpose (pitch 152 shorts) ----
      __syncthreads();
#pragma unroll
      for (int mt = 0; mt < MT; ++mt) {
        int mb = w * (MT * 16) + mt * 16 + (quad << 2);
        int ml = (mb & 64) | (((mb >> 5) & 1) << 5) | (((mb >> 2) & 3) << 3) |
                 (((mb >> 4) & 1) << 2);                  // pos-permuted coord
#pragma unroll
        for (int nt = 0; nt < 8; ++nt) {
          int nl = nt * 16 + c;
          us4 pk;
#pragma unroll
          for (int r = 0; r < 4; ++r)
            pk[r] = __builtin_bit_cast(unsigned short, (_Float16)acc[mt][nt][r]);
          *(us4*)&smem[nl * 152 + ml] = pk;
        }
      }
      __syncthreads();
      const int bb = m0 >> 12, sb = m0 & 4095;
#pragma unroll
      for (int j = 0; j < MT * 4; ++j) {
        int i = t + j * 256;
        int nl = i >> 4, mc = (i & 15) << 3;
        us8 vv = *(const us8*)&smem[nl * 152 + mc];
        int n = n0 + nl, hh = n >> 6, dk = n & 63;
        *(us8*)&vtg[((size_t)(bb * Hn + hh) * DKn + dk) * Sn + sb + mc] = vv;
      }
    } else {
#pragma unroll
      for (int mt = 0; mt < MT; ++mt)
#pragma unroll
        for (int nt = 0; nt < 8; ++nt) {
          int m = m0 + w * (MT * 16) + mt * 16 + (quad << 2);
          int n = n0 + nt * 16 + c;
          int b = m >> 12, s = m & 4095, hh = n >> 6, dk = n & 63;
          unsigned short* dst = &oh[(size_t)z * (Bn * Hn * Sn * DKn) +
                                    ((size_t)(b * Hn + hh) * Sn + s) * DKn + dk];
          unsigned pk0 = cvtpk_bf16(acc[mt][nt][0], acc[mt][nt][1]);
          unsigned pk1 = cvtpk_bf16(acc[mt][nt][2], acc[mt][nt][3]);
          dst[0] = (unsigned short)pk0;
          dst[DKn] = (unsigned short)(pk0 >> 16);
          dst[2 * DKn] = (unsigned short)pk1;
          dst[3 * DKn] = (unsigned short)(pk1 >> 16);
        }
    }
  } else {
#pragma unroll
    for (int mt = 0; mt < MT; ++mt)
#pragma unroll
      for (int nt = 0; nt < 8; ++nt)
#pragma unroll
        for (int r = 0; r < 4; ++r) {
          int m = m0 + w * (MT * 16) + mt * 16 + (quad << 2) + r;
          int n = n0 + nt * 16 + c;
          olin[(size_t)m * 512 + n] = acc[mt][nt][r];
        }
  }
}

// ------------------------------------------------------------- flash attn
// 512 thr = 2 kv-groups x 4 waves x 32 q; KVBLK=32 per group per iter, 64
// iters (vs R7's 64/32): halves LDS (68->34 KB) AND trims ~32 VGPRs (sacc
// 32->16, ph 16->8, kpre/vpre 16->8) so occupancy can rise past R7's
// register-bound 16 waves/CU. Same total MFMA work. R8 lesson: occupancy is
// EARNED by smaller reg footprint, never forced via launch_bounds (1024,8
// forced 32-VGPR cap -> 4.3 GB scratch spill, 928 us).
// R2/R3 lessons kept: prefetch immediately post-barrier; NO s_setprio here.
__global__ __launch_bounds__(512, 4) void flash_k(
    const unsigned short* __restrict__ Qh, const unsigned short* __restrict__ Kh,
    const unsigned short* __restrict__ VtG, const unsigned int* __restrict__ pmt,
    unsigned short* __restrict__ attn) {
  __shared__ unsigned short Ks[2][2][32 * 64];   // [group][parity][kv][d] 16KB
  __shared__ unsigned short Vts[2][2][64 * 32];  // [group][parity][dk][pos] 16KB
  __shared__ unsigned int Mw[2][2][128];         // 2KB
  __shared__ unsigned long long MskT[16];        // nibble -> f16x4 AND mask

  const int bid = blockIdx.x;
  const int h = bid & 7;                 // XCD = id%8 -> head h pins to XCD h
  const int b = (bid >> 3) & 1;
  const int q0 = (bid >> 4) * 128;
  const int t = threadIdx.x;
  const int g = t >> 8, tg = t & 255;
  const int w = (t >> 6) & 3, l = t & 63;
  const int quad = l >> 4, c = l & 15;
  const size_t hb = (size_t)(b * Hn + h) * Sn * DKn;
  const unsigned short* Qg = Qh + hb;

  if (t < 16) {
    unsigned lo = ((t & 1) ? 0xFFFFu : 0u) | ((t & 2) ? 0xFFFF0000u : 0u);
    unsigned hi = ((t & 4) ? 0xFFFFu : 0u) | ((t & 8) ? 0xFFFF0000u : 0u);
    MskT[t] = ((unsigned long long)hi << 32) | lo;
  }

  bf16x8 bQ[2][2];
#pragma unroll
  for (int qf = 0; qf < 2; ++qf) {
    int qrow = q0 + w * 32 + qf * 16 + c;
#pragma unroll
    for (int kc = 0; kc < 2; ++kc)
      bQ[qf][kc] = *(const bf16x8*)&Qg[(size_t)qrow * 64 + kc * 32 + quad * 8];
  }

  f32x4 oacc[2][4] = {};
  f32x4 oaccl[2] = {};                 // rowsum frag: reg r <-> q = quad*4+r
  f16x8 vone8;
#pragma unroll
  for (int i = 0; i < 8; ++i) vone8[i] = (_Float16)1.0f;

  // staging maps: K row sr (0..31) cols su*8 ; V row dkr (0..63) pos pu*8
  const int sr = tg >> 3, su = tg & 7;
  const int dkr = tg >> 2, pu = tg & 3;
  const int offK = sr * 64 + ((su ^ (sr & 7)) << 3);
  const int offV = dkr * 32 + ((pu ^ ((dkr >> 1) & 3)) << 3);

  // group g covers kv words kvw = it*2+g (32 KV each); strides: K +64 rows,
  // V pos +64, mask +2 words
  const unsigned short* kp = Kh + hb + (size_t)(g * 32 + sr) * 64 + (su << 3);
  const unsigned short* vp = VtG + hb + (size_t)dkr * Sn + g * 32 + (pu << 3);
  const unsigned int* mp =
      pmt + ((size_t)b * 128 + g) * 4096 + q0 + (tg & 127);

  us8 kpre, vpre;
  unsigned mpre;
  kpre = *(const us8*)kp;
  vpre = *(const us8*)vp;
  mpre = (tg < 128) ? *mp : 0u;
  *(us8*)&Ks[g][0][offK] = kpre;
  *(us8*)&Vts[g][0][offV] = vpre;
  if (tg < 128) Mw[g][0][tg] = mpre;

  for (int it = 0; it < 64; ++it) {
    const int cur = it & 1;
    __syncthreads();
    const bool nxt = it + 1 < 64;
    // ---- issue next-tile global prefetch FIRST (R1/R2 lesson)
    if (nxt) {
      kp += 4096; vp += 64; mp += 8192;
      kpre = *(const us8*)kp;
      vpre = *(const us8*)vp;
      if (tg < 128) mpre = *mp;
    }

    // ---- S^T = K . Q^T  (8 MFMAs)
    f32x4 sacc[2][2] = {};
#pragma unroll
    for (int kc = 0; kc < 2; ++kc) {
      int u = kc * 4 + quad;
#pragma unroll
      for (int kvt = 0; kvt < 2; ++kvt) {
        int row = kvt * 16 + c;
        bf16x8 aK =
            *(const bf16x8*)&Ks[g][cur][row * 64 + ((u ^ (c & 7)) << 3)];
#pragma unroll
        for (int qf = 0; qf < 2; ++qf)
          sacc[qf][kvt] = __builtin_amdgcn_mfma_f32_16x16x32_bf16(
              aK, bQ[qf][kc], sacc[qf][kvt], 0, 0, 0);
      }
    }

    // ---- unconditional exp2 -> packed f16, mask via LDS AND-table
    f16x8 ph[2];
#pragma unroll
    for (int qf = 0; qf < 2; ++qf) {
      int qloc = w * 32 + qf * 16 + c;
      unsigned wd = Mw[g][cur][qloc] >> (quad << 2);
      uint4 ww;
#pragma unroll
      for (int kvh = 0; kvh < 2; ++kvh) {
        const f32x4 s4 = sacc[qf][kvh];
        unsigned long long mk = MskT[(wd >> (kvh << 4)) & 15u];
        unsigned a = __builtin_bit_cast(
            unsigned, __builtin_amdgcn_cvt_pkrtz(
                          __builtin_amdgcn_exp2f(s4[0]),
                          __builtin_amdgcn_exp2f(s4[1])));
        unsigned bpk = __builtin_bit_cast(
            unsigned, __builtin_amdgcn_cvt_pkrtz(
                          __builtin_amdgcn_exp2f(s4[2]),
                          __builtin_amdgcn_exp2f(s4[3])));
        (&ww.x)[kvh * 2] = a & (unsigned)mk;
        (&ww.x)[kvh * 2 + 1] = bpk & (unsigned)(mk >> 32);
      }
      ph[qf] = __builtin_bit_cast(f16x8, ww);
    }

    // ---- O += P.V ; l += P.1  (10 MFMAs)
#pragma unroll
    for (int dkt = 0; dkt < 4; ++dkt) {
      int dk2 = dkt * 16 + c;
      f16x8 bV = __builtin_bit_cast(
          f16x8,
          *(const us8*)&Vts[g][cur][dk2 * 32 + ((quad ^ ((dk2 >> 1) & 3)) << 3)]);
#pragma unroll
      for (int qf = 0; qf < 2; ++qf)
        oacc[qf][dkt] = __builtin_amdgcn_mfma_f32_16x16x32_f16(
            ph[qf], bV, oacc[qf][dkt], 0, 0, 0);
    }
#pragma unroll
    for (int qf = 0; qf < 2; ++qf)
      oaccl[qf] = __builtin_amdgcn_mfma_f32_16x16x32_f16(
          ph[qf], vone8, oaccl[qf], 0, 0, 0);

    if (nxt) {
      const int nb = cur ^ 1;
      *(us8*)&Ks[g][nb][offK] = kpre;
      *(us8*)&Vts[g][nb][offV] = vpre;
      if (tg < 128) Mw[g][nb][tg] = mpre;
    }
  }

  // ---- combine 2 groups, per-qf passes in reused LDS (fits 34 KB)
  __syncthreads();
  float* fs = (float*)&Ks[0][0][0];            // [dkt][w][l] f32x4 = 16 KB
  float* fl = (float*)&Vts[0][0][0];           // [w][l] f32x4 = 4 KB
#pragma unroll
  for (int qf = 0; qf < 2; ++qf) {
    if (g == 1) {
#pragma unroll
      for (int dkt = 0; dkt < 4; ++dkt)
        *(f32x4*)&fs[((dkt * 4 + w) * 64 + l) * 4] = oacc[qf][dkt];
      *(f32x4*)&fl[(w * 64 + l) * 4] = oaccl[qf];
    }
    __syncthreads();
    if (g == 0) {
      f32x4 l1 = *(const f32x4*)&fl[(w * 64 + l) * 4];
#pragma unroll
      for (int r = 0; r < 4; ++r) oaccl[qf][r] += l1[r];
#pragma unroll
      for (int dkt = 0; dkt < 4; ++dkt) {
        f32x4 o1 = *(const f32x4*)&fs[((dkt * 4 + w) * 64 + l) * 4];
#pragma unroll
        for (int r = 0; r < 4; ++r) oacc[qf][dkt][r] += o1[r];
      }
    }
    __syncthreads();
  }
  if (g == 0) {
#pragma unroll
    for (int qf = 0; qf < 2; ++qf)
#pragma unroll
      for (int r = 0; r < 4; ++r) {
        float invr = 1.0f / oaccl[qf][r];
        unsigned short* dst =
            &attn[((size_t)(b * Sn + q0 + w * 32 + qf * 16 + (quad << 2) + r)) * Dn +
                  h * 64 + c];
#pragma unroll
        for (int dkt = 0; dkt < 4; ++dkt)
          dst[dkt * 16] = f2bf(oacc[qf][dkt][r] * invr);
      }
  }
}

// ------------------------------------------------------------------ launch
extern "C" void kernel_launch(void* const* d_in, const int* in_sizes, int n_in,
                              void* d_out, int out_size, void* d_ws,
                              size_t ws_size, hipStream_t stream) {
  const float* q = (const float*)d_in[0];
  const float* k = (const float*)d_in[1];
  const float* v = (const float*)d_in[2];
  const int* mask = (const int*)d_in[3];
  const float* wq = (const float*)d_in[4];
  const float* wk = (const float*)d_in[5];
  const float* wv = (const float*)d_in[6];
  const float* wo = (const float*)d_in[7];
  float* out = (float*)d_out;

  char* ws = (char*)d_ws;
  const size_t headN = (size_t)Bn * Hn * Sn * DKn;        // 4,194,304 elems
  const size_t tensB = headN * 2;                          // 8 MB
  unsigned short* attn = (unsigned short*)ws;
  size_t off = 3 * tensB;
  unsigned short* qkv = (unsigned short*)(ws + off);       // Q,K heads + V^T
  off += 3 * tensB;
  unsigned short* wt = (unsigned short*)(ws + off);        // 2 MB
  off += 4ull * 512 * 512 * 2;
  unsigned int* pm = (unsigned int*)(ws + off);            // 4 MB transposed

  prep_k<<<4352, 256, 0, stream>>>(mask, pm, wq, wk, wv, wo, wt);
  gemm_k<2, true><<<dim3(64, 4, 3), 256, 0, stream>>>(
      q, k, v, nullptr, wt, qkv, qkv + 2 * headN, nullptr);
  flash_k<<<dim3(512), 512, 0, stream>>>(qkv, qkv + headN,
                                         qkv + 2 * headN, pm, attn);
  gemm_k<1, false><<<dim3(128, 4, 1), 256, 0, stream>>>(
      nullptr, nullptr, nullptr, attn, wt + 3ull * 512 * 512, nullptr, nullptr,
      out);
}